// Round 1
// baseline (3854.382 us; speedup 1.0000x reference)
//
#include <hip/hip_runtime.h>
#include <math.h>

static constexpr int H = 256, W = 256, HW = H * W;

// ---------- activations ----------
__device__ __forceinline__ float gelu_f(float v) {
  // torch nn.GELU default (erf-based), matches jax.nn.gelu(approximate=False)
  return 0.5f * v * (1.0f + erff(v * 0.70710678118654752440f));
}

template<int ACT>
__device__ __forceinline__ float apply_act(float v) {
  if constexpr (ACT == 1) return v >= 0.f ? v : 0.1f * v;   // LeakyReLU(0.1)
  if constexpr (ACT == 2) return gelu_f(v);
  return v;
}

// ---------- 3x3 same-pad conv, NCHW, f32 ----------
// Tile: 32 wide x 16 tall output pixels per block; 256 threads, 2 rows/thread.
// Input channels staged in LDS in chunks of 16 (with 1-px halo).
// Optional 2-tensor channel concat: channels [0,cin0) from in0, rest from in1.
// Weights are read with block-uniform indices -> scalar loads (s_load).
template<int CIN, int OCPB, int ACT>
__global__ __launch_bounds__(256)
void conv3x3_k(const float* __restrict__ in0, const float* __restrict__ in1, int cin0,
               const float* __restrict__ w, const float* __restrict__ bias,
               float* __restrict__ out, int ocTotal)
{
  constexpr int CCH = 16;
  constexpr int TR = 18, TC = 34;            // tile rows/cols incl. halo
  __shared__ float lds[CCH][TR][TC];

  const int tx = threadIdx.x & 31;
  const int ty = threadIdx.x >> 5;           // 0..7
  const int x0 = blockIdx.x * 32;
  const int y0 = blockIdx.y * 16;
  const int nOcC = ocTotal / OCPB;
  const int b   = blockIdx.z / nOcC;
  const int oc0 = (blockIdx.z % nOcC) * OCPB;

  float acc[OCPB][2];
  #pragma unroll
  for (int oc = 0; oc < OCPB; ++oc) {
    float bv = bias ? bias[oc0 + oc] : 0.f;
    acc[oc][0] = bv; acc[oc][1] = bv;
  }

  #pragma unroll 1
  for (int cc = 0; cc < CIN; cc += CCH) {
    __syncthreads();
    for (int t = threadIdx.x; t < CCH * TR * TC; t += 256) {
      int c   = t / (TR * TC);
      int rem = t - c * (TR * TC);
      int r   = rem / TC;
      int col = rem - r * TC;
      int gy = y0 + r - 1, gx = x0 + col - 1;
      int ci = cc + c;
      float v = 0.f;
      if (gy >= 0 && gy < H && gx >= 0 && gx < W) {
        if (ci < cin0) v = in0[(((size_t)b * cin0 + ci) * H + gy) * W + gx];
        else           v = in1[(((size_t)b * (CIN - cin0) + (ci - cin0)) * H + gy) * W + gx];
      }
      lds[c][r][col] = v;
    }
    __syncthreads();

    #pragma unroll 2
    for (int c = 0; c < CCH; ++c) {
      float iv[4][3];
      #pragma unroll
      for (int rr = 0; rr < 4; ++rr)
        #pragma unroll
        for (int kw = 0; kw < 3; ++kw)
          iv[rr][kw] = lds[c][2 * ty + rr][tx + kw];
      #pragma unroll
      for (int oc = 0; oc < OCPB; ++oc) {
        const float* wq = w + ((size_t)(oc0 + oc) * CIN + (cc + c)) * 9;  // uniform -> s_load
        float w0 = wq[0], w1 = wq[1], w2 = wq[2],
              w3 = wq[3], w4 = wq[4], w5 = wq[5],
              w6 = wq[6], w7 = wq[7], w8 = wq[8];
        acc[oc][0] += iv[0][0]*w0 + iv[0][1]*w1 + iv[0][2]*w2
                    + iv[1][0]*w3 + iv[1][1]*w4 + iv[1][2]*w5
                    + iv[2][0]*w6 + iv[2][1]*w7 + iv[2][2]*w8;
        acc[oc][1] += iv[1][0]*w0 + iv[1][1]*w1 + iv[1][2]*w2
                    + iv[2][0]*w3 + iv[2][1]*w4 + iv[2][2]*w5
                    + iv[3][0]*w6 + iv[3][1]*w7 + iv[3][2]*w8;
      }
    }
  }

  const int ox = x0 + tx;
  #pragma unroll
  for (int oc = 0; oc < OCPB; ++oc) {
    #pragma unroll
    for (int dr = 0; dr < 2; ++dr) {
      int oy = y0 + 2 * ty + dr;
      out[(((size_t)b * ocTotal + oc0 + oc) * H + oy) * W + ox] = apply_act<ACT>(acc[oc][dr]);
    }
  }
}

// ---------- 1x1 conv, NCHW, f32 ----------
template<int CIN, int OCPB, int ACT>
__global__ __launch_bounds__(256)
void conv1x1_k(const float* __restrict__ in, const float* __restrict__ w,
               float* __restrict__ out, int ocTotal)
{
  const int p   = blockIdx.x * 256 + threadIdx.x;
  const int b   = blockIdx.y;
  const int oc0 = blockIdx.z * OCPB;
  float acc[OCPB];
  #pragma unroll
  for (int oc = 0; oc < OCPB; ++oc) acc[oc] = 0.f;
  #pragma unroll 4
  for (int ci = 0; ci < CIN; ++ci) {
    float v = in[((size_t)b * CIN + ci) * HW + p];
    #pragma unroll
    for (int oc = 0; oc < OCPB; ++oc)
      acc[oc] += v * w[(size_t)(oc0 + oc) * CIN + ci];          // uniform -> s_load
  }
  #pragma unroll
  for (int oc = 0; oc < OCPB; ++oc)
    out[((size_t)b * ocTotal + oc0 + oc) * HW + p] = apply_act<ACT>(acc[oc]);
}

// ---------- corr (einsum) + top-3 (jax tie-break: lower index wins) ----------
// warp layout: [B, 288, H, W], channel = c*9 + o. corr[o] = sum_c warp[c,o]*x[c].
__global__ __launch_bounds__(256)
void corr_topk_k(const float* __restrict__ warp, const float* __restrict__ x,
                 int* __restrict__ idxo)
{
  const int p = blockIdx.x * 256 + threadIdx.x;
  const int b = blockIdx.y;
  float corr[9];
  #pragma unroll
  for (int o = 0; o < 9; ++o) corr[o] = 0.f;
  #pragma unroll 2
  for (int c = 0; c < 32; ++c) {
    float xv = x[((size_t)b * 32 + c) * HW + p];
    const float* wp = warp + ((size_t)b * 288 + (size_t)c * 9) * HW + p;
    #pragma unroll
    for (int o = 0; o < 9; ++o) corr[o] += wp[(size_t)o * HW] * xv;
  }
  unsigned mask = 0;
  int packed = 0;
  #pragma unroll
  for (int t = 0; t < 3; ++t) {
    float best = -INFINITY; int bi = 0;
    #pragma unroll
    for (int o = 0; o < 9; ++o) {
      bool take = (((mask >> o) & 1u) == 0u) && (corr[o] > best);
      best = take ? corr[o] : best;
      bi   = take ? o       : bi;
    }
    mask   |= 1u << bi;
    packed |= bi << (4 * t);
  }
  idxo[(size_t)b * HW + p] = packed;
}

// ---------- gather selected warps + 3x3 conv with w_sel ----------
// out[b,c,p] = b_sel + sum_{t,kh,kw} w_sel[t,kh,kw] * warp[b, c*9+idx_t(q), q],
// q = neighbor pixel (zero pad outside). idx comes from the NEIGHBOR's own top-3.
__global__ __launch_bounds__(256)
void selconv_k(const float* __restrict__ warp, const int* __restrict__ idxp,
               const float* __restrict__ wsel, const float* __restrict__ bsel,
               float* __restrict__ out)
{
  const int tx = threadIdx.x & 31, ty = threadIdx.x >> 5;
  const int px = blockIdx.x * 32 + tx;
  const int py = blockIdx.y * 8 + ty;
  const int b  = blockIdx.z;

  int  nidx[9];
  bool nval[9];
  int  qoff[9];
  #pragma unroll
  for (int kh = 0; kh < 3; ++kh)
    #pragma unroll
    for (int kw = 0; kw < 3; ++kw) {
      int k = kh * 3 + kw;
      int qy = py + kh - 1, qx = px + kw - 1;
      nval[k] = (qy >= 0 && qy < H && qx >= 0 && qx < W);
      qoff[k] = qy * W + qx;
      nidx[k] = nval[k] ? idxp[(size_t)b * HW + qoff[k]] : 0;
    }

  float ws27[27];
  #pragma unroll
  for (int i = 0; i < 27; ++i) ws27[i] = wsel[i];  // uniform
  const float bs = bsel[0];

  #pragma unroll 1
  for (int c = 0; c < 32; ++c) {
    float acc = bs;
    const float* wb = warp + ((size_t)b * 288 + (size_t)c * 9) * HW;
    #pragma unroll
    for (int k = 0; k < 9; ++k) {
      if (nval[k]) {
        int pk = nidx[k];
        #pragma unroll
        for (int t = 0; t < 3; ++t) {
          int o = (pk >> (4 * t)) & 15;
          acc += ws27[t * 9 + k] * wb[(size_t)o * HW + qoff[k]];
        }
      }
    }
    out[((size_t)b * 32 + c) * HW + (size_t)py * W + px] = acc;
  }
}

// ---------- launch ----------
extern "C" void kernel_launch(void* const* d_in, const int* in_sizes, int n_in,
                              void* d_out, int out_size, void* d_ws, size_t ws_size,
                              hipStream_t stream) {
  const float* x      = (const float*)d_in[0];
  const float* key    = (const float*)d_in[1];
  const float* w_off1 = (const float*)d_in[2];
  const float* b_off1 = (const float*)d_in[3];
  const float* w_off2 = (const float*)d_in[4];
  const float* b_off2 = (const float*)d_in[5];
  const float* w_dcn  = (const float*)d_in[6];
  const float* b_dcn  = (const float*)d_in[7];
  const float* w_sel  = (const float*)d_in[8];
  const float* b_sel  = (const float*)d_in[9];
  const float* w_t1   = (const float*)d_in[10];
  const float* w_t2   = (const float*)d_in[11];
  const float* w_t3   = (const float*)d_in[12];
  const float* w_t4   = (const float*)d_in[13];
  const float* w_t5   = (const float*)d_in[14];

  // workspace layout (bytes); peak ~176.5 MiB
  char* ws = (char*)d_ws;
  float* warp = (float*)(ws);                               // [2,288,256,256] f32 = 144 MiB
  float* buf1 = (float*)(ws + 150994944);                   // 16 MiB: off1 -> gelu(y1) -> gelu(y4)
  float* buf2 = (float*)(ws + 150994944 + 16777216);        // 16 MiB: off2 -> key_warp
  int*   idxb = (int*)  (ws + 150994944 + 2*16777216);      // 0.5 MiB packed top-3
  float* y2   = (float*)(ws);                               // reuse warp region after selconv
  float* y3   = (float*)(ws + 67108864);
  float* out  = (float*)d_out;

  dim3 blk(256);

  // off = lrelu(conv3x3(concat(x,key), w_off1) + b)
  conv3x3_k<64, 16, 1><<<dim3(8, 16, 2 * 2), blk, 0, stream>>>(x, key, 32, w_off1, b_off1, buf1, 32);
  // off = lrelu(conv3x3(off, w_off2) + b)
  conv3x3_k<32, 16, 1><<<dim3(8, 16, 2 * 2), blk, 0, stream>>>(buf1, nullptr, 32, w_off2, b_off2, buf2, 32);
  // warp = conv3x3(concat(key,off), w_dcn) + b   [2,288,H,W]
  conv3x3_k<64, 16, 0><<<dim3(8, 16, 2 * 18), blk, 0, stream>>>(key, buf2, 32, w_dcn, b_dcn, warp, 288);
  // corr + top-3 per pixel
  corr_topk_k<<<dim3(HW / 256, 2), blk, 0, stream>>>(warp, x, idxb);
  // key_warp = conv over (top-3, 3x3) of gathered warps  -> buf2 (off2 dead)
  selconv_k<<<dim3(8, 32, 2), blk, 0, stream>>>(warp, idxb, w_sel, b_sel, buf2);
  // tail: y1 = conv3x3(key_warp, w_t1); store gelu(y1)
  conv3x3_k<32, 16, 2><<<dim3(8, 16, 2 * 2), blk, 0, stream>>>(buf2, nullptr, 32, w_t1, nullptr, buf1, 32);
  // y2 = conv1x1(gelu(y1), w_t2); store gelu(y2)  (warp region now dead)
  conv1x1_k<32, 32, 2><<<dim3(HW / 256, 2, 4), blk, 0, stream>>>(buf1, w_t2, y2, 128);
  // y3 = conv3x3(gelu(y2), w_t3); store gelu(y3)
  conv3x3_k<128, 16, 2><<<dim3(8, 16, 2 * 8), blk, 0, stream>>>(y2, nullptr, 128, w_t3, nullptr, y3, 128);
  // y4 = conv1x1(gelu(y3), w_t4); store gelu(y4) -> buf1 (y1 dead)
  conv1x1_k<128, 32, 2><<<dim3(HW / 256, 2, 1), blk, 0, stream>>>(y3, w_t4, buf1, 32);
  // out = conv3x3(gelu(y4), w_t5)
  conv3x3_k<32, 16, 0><<<dim3(8, 16, 2 * 2), blk, 0, stream>>>(buf1, nullptr, 32, w_t5, nullptr, out, 32);
}